// Round 10
// baseline (219.600 us; speedup 1.0000x reference)
//
#include <hip/hip_runtime.h>
#include <hip/hip_bf16.h>
#include <cstdint>
#include <cstddef>

#define GLOBAL_AS __attribute__((address_space(1)))
#define LDS_AS __attribute__((address_space(3)))

typedef short bf16x8 __attribute__((ext_vector_type(8)));
typedef float f32x4 __attribute__((ext_vector_type(4)));

constexpr int Bq = 4, Sq = 2048, Eq = 1024, Hh = 16;
constexpr int M = Bq * Sq;   // 8192
constexpr int K = 1024;
constexpr int N = 3 * Eq;    // 3072

// softmax in exp2 domain: p = 2^(s * 0.125 * log2e - 16); no overflow possible
#define SMSC 0.18033688f
#define SMBIAS (-16.0f)

#if __has_builtin(__builtin_amdgcn_exp2f)
#define EXP2F(x) __builtin_amdgcn_exp2f(x)   // bare v_exp_f32 (libm exp2f costs ~3x VALU)
#else
#define EXP2F(x) exp2f(x)
#endif

// RNE float->bf16 (finite inputs only)
static __device__ __forceinline__ unsigned f2bf(float f) {
    union { float f; unsigned u; } v; v.f = f;
    unsigned r = v.u + 0x7fffu + ((v.u >> 16) & 1u);
    return r >> 16;
}

// packed 2x f32 -> bf16 pair (v_cvt_pk_bf16_f32 on gfx950); a in low 16 bits
static __device__ __forceinline__ unsigned pk2(float a, float b) {
    union { __hip_bfloat162 h; unsigned u; } c;
    c.h = __float22bfloat162_rn(float2{a, b});
    return c.u;
}

// gfx950 cross-lane swaps (register-only, ordered by data deps)
static __device__ __forceinline__ void pl32swap(unsigned& a, unsigned& b) {
    asm("v_permlane32_swap_b32 %0, %1" : "+v"(a), "+v"(b));
}
static __device__ __forceinline__ void pl16swap(unsigned& a, unsigned& b) {
    asm("v_permlane16_swap_b32 %0, %1" : "+v"(a), "+v"(b));
}

// ---------------- prep: x fp32->bf16 (blocks 0..4095) + W transpose (blocks 4096..4863) ----
__global__ __launch_bounds__(256) void prep(const float* __restrict__ X,
                                            unsigned short* __restrict__ Xb,
                                            const float* __restrict__ W,
                                            unsigned short* __restrict__ Wt) {
    __shared__ unsigned short tile[64 * 72];
    const int t = threadIdx.x;
    const int bx = blockIdx.x;
    if (bx < 4096) {
        size_t i = ((size_t)bx * 256 + t) * 8;
        float4 a = *reinterpret_cast<const float4*>(X + i);
        float4 b = *reinterpret_cast<const float4*>(X + i + 4);
        uint4 o;
        o.x = pk2(a.x, a.y);
        o.y = pk2(a.z, a.w);
        o.z = pk2(b.x, b.y);
        o.w = pk2(b.z, b.w);
        *reinterpret_cast<uint4*>(Xb + i) = o;
        return;
    }
    const int idx = bx - 4096;
    const int n0 = (idx % 48) * 64;
    const int k0 = (idx / 48) * 64;
    #pragma unroll
    for (int p = 0; p < 4; ++p) {
        int c = p * 256 + t;
        int row = c >> 4;
        int c4 = (c & 15) * 4;
        float4 v = *reinterpret_cast<const float4*>(W + (size_t)(k0 + row) * N + n0 + c4);
        *reinterpret_cast<unsigned*>(&tile[row * 72 + c4]) = pk2(v.x, v.y);
        *reinterpret_cast<unsigned*>(&tile[row * 72 + c4 + 2]) = pk2(v.z, v.w);
    }
    __syncthreads();
    #pragma unroll
    for (int p = 0; p < 2; ++p) {
        int c = t + p * 256;
        int n = c & 63;
        int kc = (c >> 6) * 8;
        unsigned v[8];
        #pragma unroll
        for (int j = 0; j < 8; ++j) v[j] = tile[(kc + j) * 72 + n];
        uint4 o;
        o.x = v[0] | (v[1] << 16);
        o.y = v[2] | (v[3] << 16);
        o.z = v[4] | (v[5] << 16);
        o.w = v[6] | (v[7] << 16);
        *reinterpret_cast<uint4*>(Wt + (size_t)(n0 + n) * K + k0 + kc) = o;
    }
}

// ---------------- QKV GEMM: 256x128, 3-slot ring, FINE 4-phase interleave ---------------
// Round-10: r6's verified skeleton (ring + vmcnt(6) ledger) with the phase structure made
// FINE per the m201 template: 4 phases/K-tile of 8 MFMA each; per phase {ds_read only the
// subtile needed (8/4/4/0 b128 reads) ; 0-2 staging calls ; raw s_barrier ; setprio(1) ;
// 8 MFMA ; setprio(0) ; raw s_barrier}; counted vmcnt(6) ONCE per tile (phase 4), never 0
// until the drain tile. r6's coarse 2-phase variant (16-MFMA clumps, staging clumped) is
// exactly the m196-documented bad middle point (-7..-27%); this is the documented-good
// fine version. Ring safety (r6-proven): slot (kt+2)%3 is written only after its last
// reader's trailing barrier; vmcnt(6) at tile end leaves exactly tile kt+2's 6 loads in
// flight, so tile kt+1 is complete. kt=14 drains to 0; kt=15 computes the last tile.
// Grid 768 = 3x256 exact (no tail), XCD-chunked decode (768%8==0, bijective).
__global__ __launch_bounds__(512) void gemm_qkv(const unsigned short* __restrict__ A,
                                                const unsigned short* __restrict__ Bt,
                                                unsigned short* __restrict__ C,
                                                unsigned short* __restrict__ Vt) {
    __shared__ unsigned short Al[3][256 * 64];
    __shared__ unsigned short Bl[3][128 * 64];
    const int t = threadIdx.x;                 // 0..511
    const int lane = t & 63, w = t >> 6;       // 8 waves
    const int wm = w >> 1, wn = w & 1;         // 4M x 2N, per-wave 64x64
    const int lr = lane & 15, quad = lane >> 4;
    const int swz = lr & 7;

    const int bid = (int)blockIdx.x;
    const int sid = (bid & 7) * 96 + (bid >> 3);   // XCD chunking, bijective (768%8==0)
    const int nb = sid % 24, mb = sid / 24;
    const int m0 = mb * 256, n0 = nb * 128;

    auto stA = [&](int kt, int s, int p) {         // p=0..3: 64 A-rows each
        int c = p * 512 + t;
        int row = c >> 3;                          // 0..255
        int lch = (c & 7) ^ (row & 7);
        const unsigned short* g = A + (size_t)(m0 + row) * K + kt * 64 + lch * 8;
        __builtin_amdgcn_global_load_lds((const GLOBAL_AS unsigned int*)g,
                                         (LDS_AS unsigned int*)&Al[s][c * 8], 16, 0, 0);
    };
    auto stB = [&](int kt, int s, int p) {         // p=0..1: 64 B-rows each
        int c = p * 512 + t;
        int row = c >> 3;                          // 0..127
        int lch = (c & 7) ^ (row & 7);
        const unsigned short* g = Bt + (size_t)(n0 + row) * K + kt * 64 + lch * 8;
        __builtin_amdgcn_global_load_lds((const GLOBAL_AS unsigned int*)g,
                                         (LDS_AS unsigned int*)&Bl[s][c * 8], 16, 0, 0);
    };

    f32x4 acc[4][4] = {};

    // prologue: stage tiles 0 and 1 (6 calls each); vmcnt(6) -> tile 0 complete
    stA(0, 0, 0); stA(0, 0, 1); stA(0, 0, 2); stA(0, 0, 3); stB(0, 0, 0); stB(0, 0, 1);
    stA(1, 1, 0); stA(1, 1, 1); stA(1, 1, 2); stA(1, 1, 3); stB(1, 1, 0); stB(1, 1, 1);
    asm volatile("s_waitcnt vmcnt(6)" ::: "memory");
    __builtin_amdgcn_s_barrier();

    int buf = 0;
    for (int kt = 0; kt < 16; ++kt) {
        int sb = buf + 2; if (sb >= 3) sb -= 3;    // = (kt+2)%3
        const unsigned short* Ab = Al[buf];
        const unsigned short* Bb = Bl[buf];
        const bool st = (kt < 14);

        bf16x8 a0[2][2], a1[2][2], b0[2][2], b1[2][2];   // [idx][ks]

        // ---- phase 1: read a(mt01),b(nt01); stage A halves 0,1; MFMA mt01 x nt01 ----
        #pragma unroll
        for (int i2 = 0; i2 < 2; ++i2)
            #pragma unroll
            for (int ks = 0; ks < 2; ++ks) {
                const int pch = ((ks * 4 + quad) ^ swz) << 3;
                a0[i2][ks] = *reinterpret_cast<const bf16x8*>(
                    &Ab[(wm * 64 + i2 * 16 + lr) * 64 + pch]);
                b0[i2][ks] = *reinterpret_cast<const bf16x8*>(
                    &Bb[(wn * 64 + i2 * 16 + lr) * 64 + pch]);
            }
        if (st) { stA(kt + 2, sb, 0); stA(kt + 2, sb, 1); }
        __builtin_amdgcn_s_barrier();
        __builtin_amdgcn_s_setprio(1);
        #pragma unroll
        for (int mt = 0; mt < 2; ++mt)
            #pragma unroll
            for (int nt = 0; nt < 2; ++nt)
                #pragma unroll
                for (int ks = 0; ks < 2; ++ks)
                    acc[mt][nt] = __builtin_amdgcn_mfma_f32_16x16x32_bf16(
                        a0[mt][ks], b0[nt][ks], acc[mt][nt], 0, 0, 0);
        __builtin_amdgcn_s_setprio(0);
        __builtin_amdgcn_s_barrier();

        // ---- phase 2: read a(mt23); stage A halves 2,3; MFMA mt23 x nt01 ----
        #pragma unroll
        for (int i2 = 0; i2 < 2; ++i2)
            #pragma unroll
            for (int ks = 0; ks < 2; ++ks) {
                const int pch = ((ks * 4 + quad) ^ swz) << 3;
                a1[i2][ks] = *reinterpret_cast<const bf16x8*>(
                    &Ab[(wm * 64 + (2 + i2) * 16 + lr) * 64 + pch]);
            }
        if (st) { stA(kt + 2, sb, 2); stA(kt + 2, sb, 3); }
        __builtin_amdgcn_s_barrier();
        __builtin_amdgcn_s_setprio(1);
        #pragma unroll
        for (int mt = 0; mt < 2; ++mt)
            #pragma unroll
            for (int nt = 0; nt < 2; ++nt)
                #pragma unroll
                for (int ks = 0; ks < 2; ++ks)
                    acc[2 + mt][nt] = __builtin_amdgcn_mfma_f32_16x16x32_bf16(
                        a1[mt][ks], b0[nt][ks], acc[2 + mt][nt], 0, 0, 0);
        __builtin_amdgcn_s_setprio(0);
        __builtin_amdgcn_s_barrier();

        // ---- phase 3: read b(nt23); stage B halves 0,1; MFMA mt01 x nt23 ----
        #pragma unroll
        for (int i2 = 0; i2 < 2; ++i2)
            #pragma unroll
            for (int ks = 0; ks < 2; ++ks) {
                const int pch = ((ks * 4 + quad) ^ swz) << 3;
                b1[i2][ks] = *reinterpret_cast<const bf16x8*>(
                    &Bb[(wn * 64 + (2 + i2) * 16 + lr) * 64 + pch]);
            }
        if (st) { stB(kt + 2, sb, 0); stB(kt + 2, sb, 1); }
        __builtin_amdgcn_s_barrier();
        __builtin_amdgcn_s_setprio(1);
        #pragma unroll
        for (int mt = 0; mt < 2; ++mt)
            #pragma unroll
            for (int nt = 0; nt < 2; ++nt)
                #pragma unroll
                for (int ks = 0; ks < 2; ++ks)
                    acc[mt][2 + nt] = __builtin_amdgcn_mfma_f32_16x16x32_bf16(
                        a0[mt][ks], b1[nt][ks], acc[mt][2 + nt], 0, 0, 0);
        __builtin_amdgcn_s_setprio(0);
        __builtin_amdgcn_s_barrier();

        // ---- phase 4: counted vmcnt (tile kt+1 complete, kt+2 in flight); MFMA mt23 x nt23 ----
        if (kt < 14)       asm volatile("s_waitcnt vmcnt(6)" ::: "memory");
        else if (kt == 14) asm volatile("s_waitcnt vmcnt(0)" ::: "memory");
        __builtin_amdgcn_s_setprio(1);
        #pragma unroll
        for (int mt = 0; mt < 2; ++mt)
            #pragma unroll
            for (int nt = 0; nt < 2; ++nt)
                #pragma unroll
                for (int ks = 0; ks < 2; ++ks)
                    acc[2 + mt][2 + nt] = __builtin_amdgcn_mfma_f32_16x16x32_bf16(
                        a1[mt][ks], b1[nt][ks], acc[2 + mt][2 + nt], 0, 0, 0);
        __builtin_amdgcn_s_setprio(0);
        __builtin_amdgcn_s_barrier();

        buf = buf + 1 == 3 ? 0 : buf + 1;
    }

    if (n0 < 2 * Eq) {
        // Q/K columns -> qkv (row-major)
        #pragma unroll
        for (int mt = 0; mt < 4; ++mt)
            #pragma unroll
            for (int nt = 0; nt < 4; ++nt)
                #pragma unroll
                for (int r = 0; r < 4; ++r) {
                    int row = m0 + wm * 64 + mt * 16 + quad * 4 + r;
                    int col = n0 + wn * 64 + nt * 16 + lr;
                    C[(size_t)row * N + col] = (unsigned short)f2bf(acc[mt][nt][r]);
                }
    } else {
        // V columns -> Vt[b][h][d][s], 4 consecutive s per lane -> 8B packed store
        const int b2 = m0 >> 11;
        const int sbase = (m0 & 2047) + wm * 64;
        #pragma unroll
        for (int mt = 0; mt < 4; ++mt)
            #pragma unroll
            for (int nt = 0; nt < 4; ++nt) {
                int hd = n0 - 2 * Eq + wn * 64 + nt * 16 + lr;      // h*64+d
                size_t rowV = (size_t)(b2 * Hh + (hd >> 6)) * 64 + (hd & 63);
                int s = sbase + mt * 16 + quad * 4;
                uint2 val;
                val.x = f2bf(acc[mt][nt][0]) | (f2bf(acc[mt][nt][1]) << 16);
                val.y = f2bf(acc[mt][nt][2]) | (f2bf(acc[mt][nt][3]) << 16);
                *reinterpret_cast<uint2*>(Vt + rowV * Sq + s) = val;
            }
    }
}

// ---------------- Flash attention: kv-tile 32, dbuf, in-register P, CU-balanced i-map ---
// r1 structure + r9 balanced y->i map (flash fell out of the top-5 with it; kept).
// Grid = 1024 blocks = exactly 4/CU; balanced groups give every CU 136 kv-iters.
// QK^T computed SWAPPED: sa[kt][qt] = mfma(K, Q) so D has row=kv(quad*4+r), col=q(lr);
// PV A-frags built in-register with cvt_pk + permlane32/16_swap -- no LDS round-trip.
__global__ __launch_bounds__(256, 4) void flash_attn(const unsigned short* __restrict__ QKV,
                                                     const unsigned short* __restrict__ Vt,
                                                     float* __restrict__ Out) {
    __shared__ unsigned short Klds[2][32 * 64];   // [kv32][d64], XOR-swizzled chunks
    __shared__ unsigned short Vlds[2][64 * 32];   // [d64][kv32], natural
    const int t = threadIdx.x;
    const int lane = t & 63, w = t >> 6;
    const int lr = lane & 15, quad = lane >> 4;
    const int hb = blockIdx.x;
    const int h = hb & 15, b = hb >> 4;
    const int yb = (int)blockIdx.y;
    const int g = yb >> 2, pq = yb & 3;
    const int i = (g == 0) ? (15 - pq) : (g == 1) ? (8 + pq) : (g == 2) ? (7 - pq) : pq;
    const int jmax = 4 * i + 3;                // kv-tiles of 32
    const int jd = 4 * i + w;                  // this wave's diagonal kv-tile
    const int qbase = i * 128 + w * 32;
    const int sw = lr & 7;

    const unsigned short* Kbase = QKV + (size_t)b * Sq * N + Eq + h * 64;
    const unsigned short* Vbase = Vt + (size_t)((b * Hh + h) * 64) * Sq;

    bf16x8 ones;
    #pragma unroll
    for (int z = 0; z < 8; ++z) ones[z] = (short)0x3F80;

    auto stage = [&](int j, int buf) {
        const int kv0 = j * 32;
        {   // K tile: 32 rows x 64 d = 4KB, one 16B op/thread, swizzled
            int row = t >> 3;
            int lch = (t & 7) ^ (row & 7);
            const unsigned short* gk = Kbase + (size_t)(kv0 + row) * N + lch * 8;
            __builtin_amdgcn_global_load_lds((const GLOBAL_AS unsigned int*)gk,
                                             (LDS_AS unsigned int*)&Klds[buf][t * 8], 16, 0, 0);
        }
        {   // V tile: 64 d-rows x 32 kv = 4KB, natural layout
            int row = t >> 2;
            int ch = t & 3;
            const unsigned short* gv = Vbase + (size_t)row * Sq + kv0 + ch * 8;
            __builtin_amdgcn_global_load_lds((const GLOBAL_AS unsigned int*)gv,
                                             (LDS_AS unsigned int*)&Vlds[buf][t * 8], 16, 0, 0);
        }
    };

    // Q frags (B-operand: row = lane&15 = q, k = quad*8+j)
    bf16x8 qf[2][2];
    #pragma unroll
    for (int mt = 0; mt < 2; ++mt)
        #pragma unroll
        for (int ks = 0; ks < 2; ++ks)
            qf[mt][ks] = *reinterpret_cast<const bf16x8*>(
                QKV + (size_t)(b * Sq + qbase + mt * 16 + lr) * N + h * 64 + ks * 32 + quad * 8);

    f32x4 o[2][4] = {};
    f32x4 lsum[2] = {};

    stage(0, 0);
    int cur = 0;
    for (int j = 0; j <= jmax; ++j) {
        __syncthreads();              // buf[cur] staged; prior reads of cur^1 done
        if (j < jmax) stage(j + 1, cur ^ 1);

        if (j <= jd) {                // j > jd: fully masked for this wave
            const unsigned short* Kb = Klds[cur];
            const unsigned short* Vb = Vlds[cur];
            const int kv0 = j * 32;

            // S^T = K Q^T : D row=kv (quad*4+r), col=q (lr); 32kv x 32q per wave
            f32x4 sa[2][2] = {};      // [kt][qt]
            #pragma unroll
            for (int ks = 0; ks < 2; ++ks) {
                const int pch = ((ks * 4 + quad) ^ sw) << 3;
                #pragma unroll
                for (int kt = 0; kt < 2; ++kt) {
                    bf16x8 kf = *reinterpret_cast<const bf16x8*>(&Kb[(kt * 16 + lr) * 64 + pch]);
                    #pragma unroll
                    for (int qt = 0; qt < 2; ++qt)
                        sa[kt][qt] = __builtin_amdgcn_mfma_f32_16x16x32_bf16(kf, qf[qt][ks],
                                                                             sa[kt][qt], 0, 0, 0);
                }
            }

            // p = exp2(s*c - 16) in registers (bias cancels in o/lsum)
            float p[2][2][4];
            if (j == jd) {
                #pragma unroll
                for (int kt = 0; kt < 2; ++kt)
                    #pragma unroll
                    for (int qt = 0; qt < 2; ++qt)
                        #pragma unroll
                        for (int r = 0; r < 4; ++r) {
                            int kvg = kv0 + kt * 16 + quad * 4 + r;
                            int qg = qbase + qt * 16 + lr;
                            float sc = fmaf(sa[kt][qt][r], SMSC, SMBIAS);
                            sc = (kvg > qg) ? -1e30f : sc;
                            p[kt][qt][r] = EXP2F(sc);
                        }
            } else {
                #pragma unroll
                for (int kt = 0; kt < 2; ++kt)
                    #pragma unroll
                    for (int qt = 0; qt < 2; ++qt)
                        #pragma unroll
                        for (int r = 0; r < 4; ++r)
                            p[kt][qt][r] = EXP2F(fmaf(sa[kt][qt][r], SMSC, SMBIAS));
            }

            // Build PV A-frags in-register: word j2 of af must hold kv = quad*8 + 2*j2 (+1).
            bf16x8 af[2];
            #pragma unroll
            for (int qt = 0; qt < 2; ++qt) {
                unsigned w00 = pk2(p[0][qt][0], p[0][qt][1]);   // kt0, rr0
                unsigned w01 = pk2(p[0][qt][2], p[0][qt][3]);   // kt0, rr1
                unsigned w10 = pk2(p[1][qt][0], p[1][qt][1]);   // kt1, rr0
                unsigned w11 = pk2(p[1][qt][2], p[1][qt][3]);   // kt1, rr1
                pl32swap(w00, w10); pl16swap(w00, w10);         // w00 -> word0, w10 -> word2
                pl32swap(w01, w11); pl16swap(w01, w11);         // w01 -> word1, w11 -> word3
                union { unsigned u[4]; bf16x8 v; } pa;
                pa.u[0] = w00; pa.u[1] = w01; pa.u[2] = w10; pa.u[3] = w11;
                af[qt] = pa.v;
            }

            // O += P V ; lsum += P . 1  (single k=32 contraction)
            #pragma unroll
            for (int dt = 0; dt < 4; ++dt) {
                bf16x8 vf = *reinterpret_cast<const bf16x8*>(&Vb[(dt * 16 + lr) * 32 + quad * 8]);
                #pragma unroll
                for (int qt = 0; qt < 2; ++qt)
                    o[qt][dt] = __builtin_amdgcn_mfma_f32_16x16x32_bf16(af[qt], vf,
                                                                        o[qt][dt], 0, 0, 0);
            }
            #pragma unroll
            for (int qt = 0; qt < 2; ++qt)
                lsum[qt] = __builtin_amdgcn_mfma_f32_16x16x32_bf16(af[qt], ones,
                                                                   lsum[qt], 0, 0, 0);
        }
        cur ^= 1;
    }

    // epilogue: out = o / lsum (fp32)
    #pragma unroll
    for (int mt = 0; mt < 2; ++mt)
        #pragma unroll
        for (int r = 0; r < 4; ++r) {
            float inv = 1.0f / lsum[mt][r];
            int qg = qbase + mt * 16 + quad * 4 + r;
            #pragma unroll
            for (int dt = 0; dt < 4; ++dt)
                Out[(size_t)(b * Sq + qg) * Eq + h * 64 + dt * 16 + lr] = o[mt][dt][r] * inv;
        }
}

extern "C" void kernel_launch(void* const* d_in, const int* in_sizes, int n_in,
                              void* d_out, int out_size, void* d_ws, size_t ws_size,
                              hipStream_t stream) {
    const float* x  = (const float*)d_in[0];   // [M][K] fp32
    const float* Wq = (const float*)d_in[1];   // [K][N] fp32
    float* out = (float*)d_out;                // [M][E] fp32

    unsigned short* xb  = (unsigned short*)d_ws;            // M*K bf16
    unsigned short* qkv = xb + (size_t)M * K;               // M*N bf16 (V region unused)
    unsigned short* Wt  = qkv + (size_t)M * N;              // N*K bf16
    unsigned short* Vt  = Wt + (size_t)N * K;               // B*H*D*S bf16

    prep<<<dim3(4096 + 768), 256, 0, stream>>>(x, xb, Wq, Wt);
    gemm_qkv<<<dim3(768), 512, 0, stream>>>(xb, Wt, qkv, Vt);
    flash_attn<<<dim3(Hh * Bq, 16), 256, 0, stream>>>(qkv, Vt, out);
}

// Round 11
// 209.123 us; speedup vs baseline: 1.0501x; 1.0501x over previous
//
#include <hip/hip_runtime.h>
#include <hip/hip_bf16.h>
#include <cstdint>
#include <cstddef>

#define GLOBAL_AS __attribute__((address_space(1)))
#define LDS_AS __attribute__((address_space(3)))

typedef short bf16x8 __attribute__((ext_vector_type(8)));
typedef float f32x4 __attribute__((ext_vector_type(4)));

constexpr int Bq = 4, Sq = 2048, Eq = 1024, Hh = 16;
constexpr int M = Bq * Sq;   // 8192
constexpr int K = 1024;
constexpr int N = 3 * Eq;    // 3072

// softmax in exp2 domain: p = 2^(s * 0.125 * log2e - 16); no overflow possible
#define SMSC 0.18033688f
#define SMBIAS (-16.0f)

#if __has_builtin(__builtin_amdgcn_exp2f)
#define EXP2F(x) __builtin_amdgcn_exp2f(x)   // bare v_exp_f32 (libm exp2f costs ~3x VALU)
#else
#define EXP2F(x) exp2f(x)
#endif

// RNE float->bf16 (finite inputs only)
static __device__ __forceinline__ unsigned f2bf(float f) {
    union { float f; unsigned u; } v; v.f = f;
    unsigned r = v.u + 0x7fffu + ((v.u >> 16) & 1u);
    return r >> 16;
}

// packed 2x f32 -> bf16 pair (v_cvt_pk_bf16_f32 on gfx950); a in low 16 bits
static __device__ __forceinline__ unsigned pk2(float a, float b) {
    union { __hip_bfloat162 h; unsigned u; } c;
    c.h = __float22bfloat162_rn(float2{a, b});
    return c.u;
}

// gfx950 cross-lane swaps (register-only, ordered by data deps)
static __device__ __forceinline__ void pl32swap(unsigned& a, unsigned& b) {
    asm("v_permlane32_swap_b32 %0, %1" : "+v"(a), "+v"(b));
}
static __device__ __forceinline__ void pl16swap(unsigned& a, unsigned& b) {
    asm("v_permlane16_swap_b32 %0, %1" : "+v"(a), "+v"(b));
}

// ---------------- prep: x fp32->bf16 (blocks 0..4095) + W transpose (blocks 4096..4863) ----
__global__ __launch_bounds__(256) void prep(const float* __restrict__ X,
                                            unsigned short* __restrict__ Xb,
                                            const float* __restrict__ W,
                                            unsigned short* __restrict__ Wt) {
    __shared__ unsigned short tile[64 * 72];
    const int t = threadIdx.x;
    const int bx = blockIdx.x;
    if (bx < 4096) {
        size_t i = ((size_t)bx * 256 + t) * 8;
        float4 a = *reinterpret_cast<const float4*>(X + i);
        float4 b = *reinterpret_cast<const float4*>(X + i + 4);
        uint4 o;
        o.x = pk2(a.x, a.y);
        o.y = pk2(a.z, a.w);
        o.z = pk2(b.x, b.y);
        o.w = pk2(b.z, b.w);
        *reinterpret_cast<uint4*>(Xb + i) = o;
        return;
    }
    const int idx = bx - 4096;
    const int n0 = (idx % 48) * 64;
    const int k0 = (idx / 48) * 64;
    #pragma unroll
    for (int p = 0; p < 4; ++p) {
        int c = p * 256 + t;
        int row = c >> 4;
        int c4 = (c & 15) * 4;
        float4 v = *reinterpret_cast<const float4*>(W + (size_t)(k0 + row) * N + n0 + c4);
        *reinterpret_cast<unsigned*>(&tile[row * 72 + c4]) = pk2(v.x, v.y);
        *reinterpret_cast<unsigned*>(&tile[row * 72 + c4 + 2]) = pk2(v.z, v.w);
    }
    __syncthreads();
    #pragma unroll
    for (int p = 0; p < 2; ++p) {
        int c = t + p * 256;
        int n = c & 63;
        int kc = (c >> 6) * 8;
        unsigned v[8];
        #pragma unroll
        for (int j = 0; j < 8; ++j) v[j] = tile[(kc + j) * 72 + n];
        uint4 o;
        o.x = v[0] | (v[1] << 16);
        o.y = v[2] | (v[3] << 16);
        o.z = v[4] | (v[5] << 16);
        o.w = v[6] | (v[7] << 16);
        *reinterpret_cast<uint4*>(Wt + (size_t)(n0 + n) * K + k0 + kc) = o;
    }
}

// ---------------- QKV GEMM (r0/r1 single-buffer 128x128; best measured, locked) ---------
// Final session ledger for this kernel at K=1024, 8192x3072:
//   this structure (2-3 blk/CU, TLP-hidden)                = 65.0-68.0 us  <- best
//   r6  256x128 ring, coarse 2-phase counted-vmcnt (1/CU)  = 71.8 us
//   r7  128x128 double-buffer, 1 sync/tile (2/CU)          = 72.5 us
//   r10 256x128 ring, fine 4-phase counted-vmcnt (1/CU)    = 75.7 us
// With only 16 K-tiles, deep pipelines never amortize their prologue/drain and residency
// loss; cross-block TLP wins. setprio not applied (m190: null on lockstep waves).
__global__ __launch_bounds__(256) void gemm_qkv(const unsigned short* __restrict__ A,
                                                const unsigned short* __restrict__ Bt,
                                                unsigned short* __restrict__ C,
                                                unsigned short* __restrict__ Vt) {
    __shared__ unsigned short Alds[128 * 64];
    __shared__ unsigned short Blds[128 * 64];
    const int t = threadIdx.x;
    const int lane = t & 63, w = t >> 6;
    const int wm = w >> 1, wn = w & 1;
    const int m0 = blockIdx.y * 128, n0 = blockIdx.x * 128;
    const int lr = lane & 15, quad = lane >> 4;
    const int sw = lr & 7;

    f32x4 acc[4][4] = {};
    for (int k0 = 0; k0 < K; k0 += 64) {
        #pragma unroll
        for (int p = 0; p < 4; ++p) {
            int c = p * 256 + t;
            int row = c >> 3;
            int lch = (c & 7) ^ (row & 7);
            const unsigned short* ga = A + (size_t)(m0 + row) * K + k0 + lch * 8;
            __builtin_amdgcn_global_load_lds((const GLOBAL_AS unsigned int*)ga,
                                             (LDS_AS unsigned int*)&Alds[c * 8], 16, 0, 0);
            const unsigned short* gb = Bt + (size_t)(n0 + row) * K + k0 + lch * 8;
            __builtin_amdgcn_global_load_lds((const GLOBAL_AS unsigned int*)gb,
                                             (LDS_AS unsigned int*)&Blds[c * 8], 16, 0, 0);
        }
        __syncthreads();
        #pragma unroll
        for (int ks = 0; ks < 2; ++ks) {
            bf16x8 af[4], bfr[4];
            const int pch = ((ks * 4 + quad) ^ sw) << 3;
            #pragma unroll
            for (int mt = 0; mt < 4; ++mt)
                af[mt] = *reinterpret_cast<const bf16x8*>(
                    &Alds[(wm * 64 + mt * 16 + lr) * 64 + pch]);
            #pragma unroll
            for (int nt = 0; nt < 4; ++nt)
                bfr[nt] = *reinterpret_cast<const bf16x8*>(
                    &Blds[(wn * 64 + nt * 16 + lr) * 64 + pch]);
            #pragma unroll
            for (int mt = 0; mt < 4; ++mt)
                #pragma unroll
                for (int nt = 0; nt < 4; ++nt)
                    acc[mt][nt] = __builtin_amdgcn_mfma_f32_16x16x32_bf16(af[mt], bfr[nt],
                                                                          acc[mt][nt], 0, 0, 0);
        }
        __syncthreads();
    }
    if (n0 < 2 * Eq) {
        // Q/K columns -> qkv (row-major)
        #pragma unroll
        for (int mt = 0; mt < 4; ++mt)
            #pragma unroll
            for (int nt = 0; nt < 4; ++nt)
                #pragma unroll
                for (int r = 0; r < 4; ++r) {
                    int row = m0 + wm * 64 + mt * 16 + quad * 4 + r;
                    int col = n0 + wn * 64 + nt * 16 + lr;
                    C[(size_t)row * N + col] = (unsigned short)f2bf(acc[mt][nt][r]);
                }
    } else {
        // V columns -> Vt[b][h][d][s], 4 consecutive s per lane -> 8B packed store
        const int b2 = m0 >> 11;
        const int sbase = (m0 & 2047) + wm * 64;
        #pragma unroll
        for (int mt = 0; mt < 4; ++mt)
            #pragma unroll
            for (int nt = 0; nt < 4; ++nt) {
                int hd = n0 - 2 * Eq + wn * 64 + nt * 16 + lr;      // h*64+d
                size_t rowV = (size_t)(b2 * Hh + (hd >> 6)) * 64 + (hd & 63);
                int s = sbase + mt * 16 + quad * 4;
                uint2 val;
                val.x = f2bf(acc[mt][nt][0]) | (f2bf(acc[mt][nt][1]) << 16);
                val.y = f2bf(acc[mt][nt][2]) | (f2bf(acc[mt][nt][3]) << 16);
                *reinterpret_cast<uint2*>(Vt + rowV * Sq + s) = val;
            }
    }
}

// ---------------- Flash attention: kv-tile 32, dbuf, in-register P, CU-balanced i-map ---
// r1 structure + r9 balanced y->i map (with it, flash fell out of the top-5 dispatches).
// Grid = 1024 blocks = exactly 4/CU; groups {15,8,7,0},{14,9,6,1},{13,10,5,2},{12,11,4,3}
// give every CU 136 kv-iters under round-robin dispatch; long+short mix per CU lets
// early-finishers donate SIMD slots. Bijective -> correctness unconditional.
// Ledger: r2 paired (2/CU) 72.5; r3 2-wave (8/CU) 90; r4 kv64+swizzle 67.7 (conflicts 0
// but slower); r8 setprio null. This structure is latency-bound: per-tile serial chain
// {barrier, ds_read, QK-MFMA, exp, pack, PV-MFMA} ~5x the pure pipe-work; only TLP hides.
//
// QK^T computed SWAPPED: sa[kt][qt] = mfma(K, Q) so D has row=kv(quad*4+r), col=q(lr);
// PV A-frags built in-register with cvt_pk + permlane32/16_swap -- no LDS round-trip.
__global__ __launch_bounds__(256, 4) void flash_attn(const unsigned short* __restrict__ QKV,
                                                     const unsigned short* __restrict__ Vt,
                                                     float* __restrict__ Out) {
    __shared__ unsigned short Klds[2][32 * 64];   // [kv32][d64], XOR-swizzled chunks
    __shared__ unsigned short Vlds[2][64 * 32];   // [d64][kv32], natural
    const int t = threadIdx.x;
    const int lane = t & 63, w = t >> 6;
    const int lr = lane & 15, quad = lane >> 4;
    const int hb = blockIdx.x;
    const int h = hb & 15, b = hb >> 4;
    const int yb = (int)blockIdx.y;
    const int g = yb >> 2, pq = yb & 3;
    const int i = (g == 0) ? (15 - pq) : (g == 1) ? (8 + pq) : (g == 2) ? (7 - pq) : pq;
    const int jmax = 4 * i + 3;                // kv-tiles of 32
    const int jd = 4 * i + w;                  // this wave's diagonal kv-tile
    const int qbase = i * 128 + w * 32;
    const int sw = lr & 7;

    const unsigned short* Kbase = QKV + (size_t)b * Sq * N + Eq + h * 64;
    const unsigned short* Vbase = Vt + (size_t)((b * Hh + h) * 64) * Sq;

    bf16x8 ones;
    #pragma unroll
    for (int z = 0; z < 8; ++z) ones[z] = (short)0x3F80;

    auto stage = [&](int j, int buf) {
        const int kv0 = j * 32;
        {   // K tile: 32 rows x 64 d = 4KB, one 16B op/thread, swizzled
            int row = t >> 3;
            int lch = (t & 7) ^ (row & 7);
            const unsigned short* gk = Kbase + (size_t)(kv0 + row) * N + lch * 8;
            __builtin_amdgcn_global_load_lds((const GLOBAL_AS unsigned int*)gk,
                                             (LDS_AS unsigned int*)&Klds[buf][t * 8], 16, 0, 0);
        }
        {   // V tile: 64 d-rows x 32 kv = 4KB, natural layout
            int row = t >> 2;
            int ch = t & 3;
            const unsigned short* gv = Vbase + (size_t)row * Sq + kv0 + ch * 8;
            __builtin_amdgcn_global_load_lds((const GLOBAL_AS unsigned int*)gv,
                                             (LDS_AS unsigned int*)&Vlds[buf][t * 8], 16, 0, 0);
        }
    };

    // Q frags (B-operand: row = lane&15 = q, k = quad*8+j)
    bf16x8 qf[2][2];
    #pragma unroll
    for (int mt = 0; mt < 2; ++mt)
        #pragma unroll
        for (int ks = 0; ks < 2; ++ks)
            qf[mt][ks] = *reinterpret_cast<const bf16x8*>(
                QKV + (size_t)(b * Sq + qbase + mt * 16 + lr) * N + h * 64 + ks * 32 + quad * 8);

    f32x4 o[2][4] = {};
    f32x4 lsum[2] = {};

    stage(0, 0);
    int cur = 0;
    for (int j = 0; j <= jmax; ++j) {
        __syncthreads();              // buf[cur] staged; prior reads of cur^1 done
        if (j < jmax) stage(j + 1, cur ^ 1);

        if (j <= jd) {                // j > jd: fully masked for this wave
            const unsigned short* Kb = Klds[cur];
            const unsigned short* Vb = Vlds[cur];
            const int kv0 = j * 32;

            // S^T = K Q^T : D row=kv (quad*4+r), col=q (lr); 32kv x 32q per wave
            f32x4 sa[2][2] = {};      // [kt][qt]
            #pragma unroll
            for (int ks = 0; ks < 2; ++ks) {
                const int pch = ((ks * 4 + quad) ^ sw) << 3;
                #pragma unroll
                for (int kt = 0; kt < 2; ++kt) {
                    bf16x8 kf = *reinterpret_cast<const bf16x8*>(&Kb[(kt * 16 + lr) * 64 + pch]);
                    #pragma unroll
                    for (int qt = 0; qt < 2; ++qt)
                        sa[kt][qt] = __builtin_amdgcn_mfma_f32_16x16x32_bf16(kf, qf[qt][ks],
                                                                             sa[kt][qt], 0, 0, 0);
                }
            }

            // p = exp2(s*c - 16) in registers (bias cancels in o/lsum)
            float p[2][2][4];
            if (j == jd) {
                #pragma unroll
                for (int kt = 0; kt < 2; ++kt)
                    #pragma unroll
                    for (int qt = 0; qt < 2; ++qt)
                        #pragma unroll
                        for (int r = 0; r < 4; ++r) {
                            int kvg = kv0 + kt * 16 + quad * 4 + r;
                            int qg = qbase + qt * 16 + lr;
                            float sc = fmaf(sa[kt][qt][r], SMSC, SMBIAS);
                            sc = (kvg > qg) ? -1e30f : sc;
                            p[kt][qt][r] = EXP2F(sc);
                        }
            } else {
                #pragma unroll
                for (int kt = 0; kt < 2; ++kt)
                    #pragma unroll
                    for (int qt = 0; qt < 2; ++qt)
                        #pragma unroll
                        for (int r = 0; r < 4; ++r)
                            p[kt][qt][r] = EXP2F(fmaf(sa[kt][qt][r], SMSC, SMBIAS));
            }

            // Build PV A-frags in-register: word j2 of af must hold kv = quad*8 + 2*j2 (+1).
            bf16x8 af[2];
            #pragma unroll
            for (int qt = 0; qt < 2; ++qt) {
                unsigned w00 = pk2(p[0][qt][0], p[0][qt][1]);   // kt0, rr0
                unsigned w01 = pk2(p[0][qt][2], p[0][qt][3]);   // kt0, rr1
                unsigned w10 = pk2(p[1][qt][0], p[1][qt][1]);   // kt1, rr0
                unsigned w11 = pk2(p[1][qt][2], p[1][qt][3]);   // kt1, rr1
                pl32swap(w00, w10); pl16swap(w00, w10);         // w00 -> word0, w10 -> word2
                pl32swap(w01, w11); pl16swap(w01, w11);         // w01 -> word1, w11 -> word3
                union { unsigned u[4]; bf16x8 v; } pa;
                pa.u[0] = w00; pa.u[1] = w01; pa.u[2] = w10; pa.u[3] = w11;
                af[qt] = pa.v;
            }

            // O += P V ; lsum += P . 1  (single k=32 contraction)
            #pragma unroll
            for (int dt = 0; dt < 4; ++dt) {
                bf16x8 vf = *reinterpret_cast<const bf16x8*>(&Vb[(dt * 16 + lr) * 32 + quad * 8]);
                #pragma unroll
                for (int qt = 0; qt < 2; ++qt)
                    o[qt][dt] = __builtin_amdgcn_mfma_f32_16x16x32_bf16(af[qt], vf,
                                                                        o[qt][dt], 0, 0, 0);
            }
            #pragma unroll
            for (int qt = 0; qt < 2; ++qt)
                lsum[qt] = __builtin_amdgcn_mfma_f32_16x16x32_bf16(af[qt], ones,
                                                                   lsum[qt], 0, 0, 0);
        }
        cur ^= 1;
    }

    // epilogue: out = o / lsum (fp32)
    #pragma unroll
    for (int mt = 0; mt < 2; ++mt)
        #pragma unroll
        for (int r = 0; r < 4; ++r) {
            float inv = 1.0f / lsum[mt][r];
            int qg = qbase + mt * 16 + quad * 4 + r;
            #pragma unroll
            for (int dt = 0; dt < 4; ++dt)
                Out[(size_t)(b * Sq + qg) * Eq + h * 64 + dt * 16 + lr] = o[mt][dt][r] * inv;
        }
}

extern "C" void kernel_launch(void* const* d_in, const int* in_sizes, int n_in,
                              void* d_out, int out_size, void* d_ws, size_t ws_size,
                              hipStream_t stream) {
    const float* x  = (const float*)d_in[0];   // [M][K] fp32
    const float* Wq = (const float*)d_in[1];   // [K][N] fp32
    float* out = (float*)d_out;                // [M][E] fp32

    unsigned short* xb  = (unsigned short*)d_ws;            // M*K bf16
    unsigned short* qkv = xb + (size_t)M * K;               // M*N bf16 (V region unused)
    unsigned short* Wt  = qkv + (size_t)M * N;              // N*K bf16
    unsigned short* Vt  = Wt + (size_t)N * K;               // B*H*D*S bf16

    prep<<<dim3(4096 + 768), 256, 0, stream>>>(x, xb, Wq, Wt);
    gemm_qkv<<<dim3(N / 128, M / 128), 256, 0, stream>>>(xb, Wt, qkv, Vt);
    flash_attn<<<dim3(Hh * Bq, 16), 256, 0, stream>>>(qkv, Vt, out);
}